// Round 20
// baseline (159.275 us; speedup 1.0000x reference)
//
#include <hip/hip_runtime.h>
#include <hip/hip_bf16.h>

// B=32, C=32, H=W=256, regions 4x4 of 64x64.
// Round 20: r19 (156.4us) with 16-row conv tiles. Conv is VGPR-bound
// (~140 regs -> 8 waves/CU), so LDS 40->73.7KB is occupancy-free; gains:
// halo 1.25x->1.125x (-26MB L3 reads), half the finalize chains/block
// overheads (4096->2048 blocks), Bc warm-up amortized over 16 rows.
// Staging 2-deep with register reuse (peak staging VGPR unchanged).

#define EPS 1e-5f

typedef float f32x4 __attribute__((ext_vector_type(4)));
typedef __bf16 bf16x8 __attribute__((ext_vector_type(8)));
typedef short short8 __attribute__((ext_vector_type(8)));

__device__ inline short f2bf(float f) {
  union { __hip_bfloat16 h; short s; } u;
  u.h = __float2bfloat16(f);
  return u.s;
}

// ---------------- Kernel 1: stats partials (+ weights prep in tail blocks) --
// blocks 0..1023: per-(b,c) plane stats -> ws[(p*32+c)*32+b].
// blocks 1024..1028: pack conv_w into MFMA A-fragments.
__global__ __launch_bounds__(256) void stats_prep(
    const float* __restrict__ x, float* __restrict__ ws_sum,
    float* __restrict__ ws_sq, const float* __restrict__ conv_w,
    unsigned short* __restrict__ wfrag) {
  int blk = blockIdx.x;
  int t = threadIdx.x;

  if (blk >= 1024) {                 // ---- weights_prep tail
    int idx = (blk - 1024) * 256 + t;
    if (idx < 18 * 64) {
      int lane = idx & 63;
      int th = idx >> 6;             // t*2 + h
      int tt = th >> 1, h = th & 1;
      int dy = tt / 3, dx = tt - dy * 3;
      int oc = h * 16 + (lane & 15);
      int ic0 = (lane >> 4) * 8;
#pragma unroll
      for (int j = 0; j < 8; ++j) {
        float w = conv_w[((oc * 32 + ic0 + j) * 3 + dy) * 3 + dx];
        wfrag[(size_t)idx * 8 + j] = (unsigned short)f2bf(w);
      }
    }
    return;
  }

  int plane = blk;                   // b*32 + c
  int b = plane >> 5, c = plane & 31;
  const float* base = x + (size_t)plane * 65536;
  float s[4] = {0.f, 0.f, 0.f, 0.f}, q[4] = {0.f, 0.f, 0.f, 0.f};
#pragma unroll
  for (int R = 0; R < 4; ++R) {
#pragma unroll
    for (int ii = 0; ii < 16; ++ii) {
      int idx4 = (R * 16 + ii) * 256 + t;     // float4 index
      float4 v = *reinterpret_cast<const float4*>(base + (size_t)idx4 * 4);
      s[R] += (v.x + v.y) + (v.z + v.w);
      q[R] += (v.x * v.x + v.y * v.y) + (v.z * v.z + v.w * v.w);
    }
  }
#pragma unroll
  for (int R = 0; R < 4; ++R) {
#pragma unroll
    for (int off = 8; off; off >>= 1) {
      s[R] += __shfl_down(s[R], off);
      q[R] += __shfl_down(q[R], off);
    }
  }
  __shared__ float red[2][4][4][4];  // [s|q][wave][Cc][R]
  int lane = t & 63, wv = t >> 6;
  if ((lane & 15) == 0) {
    int Cc = lane >> 4;
#pragma unroll
    for (int R = 0; R < 4; ++R) {
      red[0][wv][Cc][R] = s[R];
      red[1][wv][Cc][R] = q[R];
    }
  }
  __syncthreads();
  if (t < 16) {                      // t == p; ws layout [p][c][b]
    int R = t >> 2, Cc = t & 3;
    float S = 0.f, Q = 0.f;
#pragma unroll
    for (int w = 0; w < 4; ++w) {
      S += red[0][w][Cc][R];
      Q += red[1][w][Cc][R];
    }
    ws_sum[(t * 32 + c) * 32 + b] = S;
    ws_sq[(t * 32 + c) * 32 + b] = Q;
  }
}

// ---------------- Kernel 2: finalize + normalize+prelu -> LDS -> MFMA -------
// block = (b, p, rt): 16 output rows x 64 cols of one region. 4 waves.
// LDS: [18 rows][64 physcols][4 slots x 8 ic] bf16 = 73728 B.
// Physical col P(c) = (c&~3) | ((c + (c>>2)) & 3); slot = (ic/8 + P>>1) & 3.
__global__ __launch_bounds__(256) void conv_mfma(
    const float* __restrict__ x, const unsigned short* __restrict__ wfrag,
    const float* __restrict__ conv_b, const float* __restrict__ prelu_a,
    const float* __restrict__ ws_sum, const float* __restrict__ ws_sq,
    const float* __restrict__ gamma, const float* __restrict__ beta,
    float* __restrict__ out) {
  __shared__ short lds_y[18 * 64 * 32];  // 73728 B -> 2 blocks/CU (LDS)

  int blk0 = blockIdx.x;             // 2048 blocks; chunked XCD swizzle
  int blk = (blk0 & 7) * 256 + (blk0 >> 3);
  int rt = blk & 3;
  int p = (blk >> 2) & 15;
  int b = blk >> 6;
  int R = p >> 2, Cc = p & 3;
  int h0 = rt * 16;
  int tid = threadIdx.x;
  int lane = tid & 63;
  float pa = prelu_a[0];

  // per-thread-fixed staging decomposition
  int s = (tid >> 4) & 3;            // ic-slice
  int c4 = tid & 15;                 // col-quad
  int srb = tid >> 6;                // base staged-row 0..3
  int ic0 = s * 8;

  // ---- staging helpers
  auto stage_load = [&](f32x4(&vv)[8], int sr) {
    int lr = h0 - 1 + sr;
#pragma unroll
    for (int kk = 0; kk < 8; ++kk) vv[kk] = f32x4{0.f, 0.f, 0.f, 0.f};
    if ((unsigned)lr < 64u) {
      const float* xp =
          x + (((size_t)(b * 32 + ic0) * 256 + R * 64 + lr) * 256) + Cc * 64 +
          c4 * 4;
#pragma unroll
      for (int kk = 0; kk < 8; ++kk)
        vv[kk] = *reinterpret_cast<const f32x4*>(xp + (size_t)kk * 65536);
    }
  };

  // ---- issue first 16 x-loads; they stay in flight across the finalize
  f32x4 va[8], vb[8];
  stage_load(va, srb);
  stage_load(vb, srb + 4);

  // ---- local finalize: per-channel scale/shift for region p (32 threads)
  // ws layout [p][c][b]: thread c reads a contiguous 32-float run.
  float* abuf = (float*)lds_y;       // [0..31]=a, [32..63]=b; freed below
  if (tid < 32) {
    int c = tid;
    const float* su = ws_sum + (p * 32 + c) * 32;
    const float* sq = ws_sq + (p * 32 + c) * 32;
    float S = 0.f, Q = 0.f;
#pragma unroll
    for (int bb = 0; bb < 32; ++bb) {
      S += su[bb];
      Q += sq[bb];
    }
    const float inv = 1.0f / 131072.0f;
    float mean = S * inv;
    float var = Q * inv - mean * mean;
    float rstd = rsqrtf(var + EPS);
    float a = rstd * gamma[c];
    abuf[c] = a;
    abuf[32 + c] = beta[c] - mean * a;
  }
  __syncthreads();

  float a_r[8], b_r[8];
#pragma unroll
  for (int j = 0; j < 8; ++j) {
    a_r[j] = abuf[ic0 + j];
    b_r[j] = abuf[32 + ic0 + j];
  }
  __syncthreads();                   // abuf consumed; LDS free for staging

  auto stage_write = [&](const f32x4(&vv)[8], int sr) {
#pragma unroll
    for (int j = 0; j < 4; ++j) {
      short8 pk;
#pragma unroll
      for (int kk = 0; kk < 8; ++kk) {
        float e = fmaf(a_r[kk], vv[kk][j], b_r[kk]);
        e = e > 0.f ? e : pa * e;
        pk[kk] = f2bf(e);
      }
      // physical col: rotate within quad by quad index -> conflict-free write
      int colp = c4 * 4 + ((j + c4) & 3);
      int slot = (s + (colp >> 1)) & 3;
      *reinterpret_cast<short8*>(&lds_y[(sr * 64 + colp) * 32 + slot * 8]) = pk;
    }
  };

  // ---- staged rows srb, srb+4, srb+8, srb+12 (all), srb+16 (tid<128):
  // 2-deep pipeline with register reuse (va/vb recycled).
  stage_write(va, srb);
  stage_load(va, srb + 8);
  stage_write(vb, srb + 4);
  stage_load(vb, srb + 12);
  stage_write(va, srb + 8);
  if (tid < 128) stage_load(va, srb + 16);   // rows 16,17
  stage_write(vb, srb + 12);
  if (tid < 128) stage_write(va, srb + 16);
  __syncthreads();

  // ---- weight fragments + bias (post-barrier: lower VGPR during staging)
  bf16x8 wf[18];
#pragma unroll
  for (int th = 0; th < 18; ++th) {
    short8 sv =
        *reinterpret_cast<const short8*>(wfrag + ((size_t)th * 64 + lane) * 8);
    wf[th] = __builtin_bit_cast(bf16x8, sv);
  }
  int l15 = lane & 15, l4 = lane >> 4;
  f32x4 bias0, bias1;
#pragma unroll
  for (int i = 0; i < 4; ++i) {
    bias0[i] = conv_b[l4 * 4 + i];
    bias1[i] = conv_b[16 + l4 * 4 + i];
  }

  // ---- MFMA with row-sliding B-frag cache: wave owns col-block c0=wv*16,
  // slides r=0..15; 3 new ds_reads per step.
  int wv = tid >> 6;
  int c0 = wv * 16;
  const short8 z8 = {0, 0, 0, 0, 0, 0, 0, 0};
  bool kill0 = (c0 == 0 && l15 == 0);      // global col -1 -> zero
  bool kill2 = (c0 == 48 && l15 == 15);    // global col 64 -> zero

  bf16x8 Bc[3][3];                   // [sr%3][dx], static idx after unroll
  auto load_row = [&](int sr, int rm) {
#pragma unroll
    for (int dx = 0; dx < 3; ++dx) {
      int colc = (c0 + l15 + dx - 1) & 63;
      int colp = (colc & ~3) | ((colc + (colc >> 2)) & 3);
      int slot = (l4 + (colp >> 1)) & 3;
      short8 sv = *reinterpret_cast<const short8*>(
          &lds_y[(sr * 64 + colp) * 32 + slot * 8]);
      if (dx == 0 && kill0) sv = z8;
      if (dx == 2 && kill2) sv = z8;
      Bc[rm][dx] = __builtin_bit_cast(bf16x8, sv);
    }
  };

  load_row(0, 0);
  load_row(1, 1);
#pragma unroll
  for (int r = 0; r < 16; ++r) {
    load_row(r + 2, (r + 2) % 3);
    f32x4 acc0 = bias0, acc1 = bias1;
#pragma unroll
    for (int t9 = 0; t9 < 9; ++t9) {
      const int dy = t9 / 3, dx = t9 - dy * 3;
      const int rm = (r + dy) % 3;   // compile-time in unrolled body
      acc0 = __builtin_amdgcn_mfma_f32_16x16x32_bf16(wf[t9 * 2], Bc[rm][dx],
                                                     acc0, 0, 0, 0);
      acc1 = __builtin_amdgcn_mfma_f32_16x16x32_bf16(wf[t9 * 2 + 1],
                                                     Bc[rm][dx], acc1, 0, 0, 0);
    }
    int grow = R * 64 + h0 + r;
    int gcol = Cc * 64 + c0 + l15;
    float* ob = out + (size_t)b * 2097152 + (size_t)grow * 256 + gcol;
#pragma unroll
    for (int i = 0; i < 4; ++i) {
      __builtin_nontemporal_store(acc0[i], &ob[(size_t)(l4 * 4 + i) * 65536]);
      __builtin_nontemporal_store(acc1[i],
                                  &ob[(size_t)(16 + l4 * 4 + i) * 65536]);
    }
  }
}

extern "C" void kernel_launch(void* const* d_in, const int* in_sizes, int n_in,
                              void* d_out, int out_size, void* d_ws,
                              size_t ws_size, hipStream_t stream) {
  const float* x = (const float*)d_in[0];
  const float* gamma = (const float*)d_in[1];
  const float* beta = (const float*)d_in[2];
  const float* prelu_a = (const float*)d_in[3];
  const float* conv_w = (const float*)d_in[4];
  const float* conv_b = (const float*)d_in[5];
  float* out = (float*)d_out;

  float* ws = (float*)d_ws;
  float* ws_sum = ws;                          // 16384 floats
  float* ws_sq = ws + 16384;                   // 16384
  unsigned short* wfrag = (unsigned short*)(ws + 32768);   // 9216 shorts

  stats_prep<<<1029, 256, 0, stream>>>(x, ws_sum, ws_sq, conv_w, wfrag);
  conv_mfma<<<2048, 256, 0, stream>>>(x, wfrag, conv_b, prelu_a, ws_sum, ws_sq,
                                      gamma, beta, out);
}

// Round 21
// 151.415 us; speedup vs baseline: 1.0519x; 1.0519x over previous
//
#include <hip/hip_runtime.h>
#include <hip/hip_bf16.h>

// B=32, C=32, H=W=256, regions 4x4 of 64x64.
// FINAL (= round 19, best measured 156.4us; r20's 16-row tile regressed).
// Structure: stats+prep fused launch, then conv_mfma per (b,p,8-row tile):
//  - nt out-stores (keep x L3-resident; -18us, r14)
//  - write-conflict-free LDS column permutation P(c) (-7us, r17)
//  - staging x-loads issued before the per-block finalize (-5us, r18)
//  - row-sliding B-fragment register cache, 30 vs 72 ds_reads (-4us, r19)
//  - 3-deep pipelined staging, ic-slot swizzle, XCD-chunked block swizzle.

#define EPS 1e-5f

typedef float f32x4 __attribute__((ext_vector_type(4)));
typedef __bf16 bf16x8 __attribute__((ext_vector_type(8)));
typedef short short8 __attribute__((ext_vector_type(8)));

__device__ inline short f2bf(float f) {
  union { __hip_bfloat16 h; short s; } u;
  u.h = __float2bfloat16(f);
  return u.s;
}

// ---------------- Kernel 1: stats partials (+ weights prep in tail blocks) --
// blocks 0..1023: per-(b,c) plane stats -> ws[(p*32+c)*32+b].
// blocks 1024..1028: pack conv_w into MFMA A-fragments.
__global__ __launch_bounds__(256) void stats_prep(
    const float* __restrict__ x, float* __restrict__ ws_sum,
    float* __restrict__ ws_sq, const float* __restrict__ conv_w,
    unsigned short* __restrict__ wfrag) {
  int blk = blockIdx.x;
  int t = threadIdx.x;

  if (blk >= 1024) {                 // ---- weights_prep tail
    int idx = (blk - 1024) * 256 + t;
    if (idx < 18 * 64) {
      int lane = idx & 63;
      int th = idx >> 6;             // t*2 + h
      int tt = th >> 1, h = th & 1;
      int dy = tt / 3, dx = tt - dy * 3;
      int oc = h * 16 + (lane & 15);
      int ic0 = (lane >> 4) * 8;
#pragma unroll
      for (int j = 0; j < 8; ++j) {
        float w = conv_w[((oc * 32 + ic0 + j) * 3 + dy) * 3 + dx];
        wfrag[(size_t)idx * 8 + j] = (unsigned short)f2bf(w);
      }
    }
    return;
  }

  int plane = blk;                   // b*32 + c
  int b = plane >> 5, c = plane & 31;
  const float* base = x + (size_t)plane * 65536;
  float s[4] = {0.f, 0.f, 0.f, 0.f}, q[4] = {0.f, 0.f, 0.f, 0.f};
#pragma unroll
  for (int R = 0; R < 4; ++R) {
#pragma unroll
    for (int ii = 0; ii < 16; ++ii) {
      int idx4 = (R * 16 + ii) * 256 + t;     // float4 index
      float4 v = *reinterpret_cast<const float4*>(base + (size_t)idx4 * 4);
      s[R] += (v.x + v.y) + (v.z + v.w);
      q[R] += (v.x * v.x + v.y * v.y) + (v.z * v.z + v.w * v.w);
    }
  }
#pragma unroll
  for (int R = 0; R < 4; ++R) {
#pragma unroll
    for (int off = 8; off; off >>= 1) {
      s[R] += __shfl_down(s[R], off);
      q[R] += __shfl_down(q[R], off);
    }
  }
  __shared__ float red[2][4][4][4];  // [s|q][wave][Cc][R]
  int lane = t & 63, wv = t >> 6;
  if ((lane & 15) == 0) {
    int Cc = lane >> 4;
#pragma unroll
    for (int R = 0; R < 4; ++R) {
      red[0][wv][Cc][R] = s[R];
      red[1][wv][Cc][R] = q[R];
    }
  }
  __syncthreads();
  if (t < 16) {                      // t == p; ws layout [p][c][b]
    int R = t >> 2, Cc = t & 3;
    float S = 0.f, Q = 0.f;
#pragma unroll
    for (int w = 0; w < 4; ++w) {
      S += red[0][w][Cc][R];
      Q += red[1][w][Cc][R];
    }
    ws_sum[(t * 32 + c) * 32 + b] = S;
    ws_sq[(t * 32 + c) * 32 + b] = Q;
  }
}

// ---------------- Kernel 2: finalize + normalize+prelu -> LDS -> MFMA -------
// block = (b, p, rt): 8 output rows x 64 cols of one region. 4 waves.
// LDS: [10 rows][64 physcols][4 slots x 8 ic] bf16.
// Physical col P(c) = (c&~3) | ((c + (c>>2)) & 3); slot = (ic/8 + P>>1) & 3.
__global__ __launch_bounds__(256) void conv_mfma(
    const float* __restrict__ x, const unsigned short* __restrict__ wfrag,
    const float* __restrict__ conv_b, const float* __restrict__ prelu_a,
    const float* __restrict__ ws_sum, const float* __restrict__ ws_sq,
    const float* __restrict__ gamma, const float* __restrict__ beta,
    float* __restrict__ out) {
  __shared__ short lds_y[10 * 64 * 32];  // 40960 B -> 4 blocks/CU

  int blk0 = blockIdx.x;             // 4096 blocks; chunked XCD swizzle
  int blk = (blk0 & 7) * 512 + (blk0 >> 3);
  int rt = blk & 7;
  int p = (blk >> 3) & 15;
  int b = blk >> 7;
  int R = p >> 2, Cc = p & 3;
  int h0 = rt * 8;
  int tid = threadIdx.x;
  int lane = tid & 63;
  float pa = prelu_a[0];

  // per-thread-fixed staging decomposition
  int s = (tid >> 4) & 3;            // ic-slice
  int c4 = tid & 15;                 // col-quad
  int srb = tid >> 6;                // base staged-row
  int ic0 = s * 8;

  // ---- staging helpers
  auto stage_load = [&](f32x4(&vv)[8], int sr) {
    int lr = h0 - 1 + sr;
#pragma unroll
    for (int kk = 0; kk < 8; ++kk) vv[kk] = f32x4{0.f, 0.f, 0.f, 0.f};
    if ((unsigned)lr < 64u) {
      const float* xp =
          x + (((size_t)(b * 32 + ic0) * 256 + R * 64 + lr) * 256) + Cc * 64 +
          c4 * 4;
#pragma unroll
      for (int kk = 0; kk < 8; ++kk)
        vv[kk] = *reinterpret_cast<const f32x4*>(xp + (size_t)kk * 65536);
    }
  };

  // ---- issue first 16 x-loads; they stay in flight across the finalize
  f32x4 va[8], vb[8];
  stage_load(va, srb);
  stage_load(vb, srb + 4);

  // ---- local finalize: per-channel scale/shift for region p (32 threads)
  // ws layout [p][c][b]: thread c reads a contiguous 32-float run.
  float* abuf = (float*)lds_y;       // [0..31]=a, [32..63]=b; freed below
  if (tid < 32) {
    int c = tid;
    const float* su = ws_sum + (p * 32 + c) * 32;
    const float* sq = ws_sq + (p * 32 + c) * 32;
    float S = 0.f, Q = 0.f;
#pragma unroll
    for (int bb = 0; bb < 32; ++bb) {
      S += su[bb];
      Q += sq[bb];
    }
    const float inv = 1.0f / 131072.0f;
    float mean = S * inv;
    float var = Q * inv - mean * mean;
    float rstd = rsqrtf(var + EPS);
    float a = rstd * gamma[c];
    abuf[c] = a;
    abuf[32 + c] = beta[c] - mean * a;
  }
  __syncthreads();

  float a_r[8], b_r[8];
#pragma unroll
  for (int j = 0; j < 8; ++j) {
    a_r[j] = abuf[ic0 + j];
    b_r[j] = abuf[32 + ic0 + j];
  }
  __syncthreads();                   // abuf consumed; LDS free for staging

  auto stage_write = [&](const f32x4(&vv)[8], int sr) {
#pragma unroll
    for (int j = 0; j < 4; ++j) {
      short8 pk;
#pragma unroll
      for (int kk = 0; kk < 8; ++kk) {
        float e = fmaf(a_r[kk], vv[kk][j], b_r[kk]);
        e = e > 0.f ? e : pa * e;
        pk[kk] = f2bf(e);
      }
      // physical col: rotate within quad by quad index -> conflict-free write
      int colp = c4 * 4 + ((j + c4) & 3);
      int slot = (s + (colp >> 1)) & 3;
      *reinterpret_cast<short8*>(&lds_y[(sr * 64 + colp) * 32 + slot * 8]) = pk;
    }
  };

  // ---- drain the pipelined staging
  {
    f32x4 vc[8];
    stage_write(va, srb);
    if (tid < 128) stage_load(vc, srb + 8);
    stage_write(vb, srb + 4);
    if (tid < 128) stage_write(vc, srb + 8);
  }
  __syncthreads();

  // ---- weight fragments + bias (post-barrier: lower VGPR during staging)
  bf16x8 wf[18];
#pragma unroll
  for (int th = 0; th < 18; ++th) {
    short8 sv =
        *reinterpret_cast<const short8*>(wfrag + ((size_t)th * 64 + lane) * 8);
    wf[th] = __builtin_bit_cast(bf16x8, sv);
  }
  int l15 = lane & 15, l4 = lane >> 4;
  f32x4 bias0, bias1;
#pragma unroll
  for (int i = 0; i < 4; ++i) {
    bias0[i] = conv_b[l4 * 4 + i];
    bias1[i] = conv_b[16 + l4 * 4 + i];
  }

  // ---- MFMA with row-sliding B-frag cache: wave owns col-block c0=wv*16,
  // slides r=0..7; only 3 new ds_reads per step (30 total vs 72).
  int wv = tid >> 6;
  int c0 = wv * 16;
  const short8 z8 = {0, 0, 0, 0, 0, 0, 0, 0};
  bool kill0 = (c0 == 0 && l15 == 0);      // global col -1 -> zero
  bool kill2 = (c0 == 48 && l15 == 15);    // global col 64 -> zero

  bf16x8 Bc[3][3];                   // [sr%3][dx], static idx after unroll
  auto load_row = [&](int sr, int rm) {
#pragma unroll
    for (int dx = 0; dx < 3; ++dx) {
      int colc = (c0 + l15 + dx - 1) & 63;
      int colp = (colc & ~3) | ((colc + (colc >> 2)) & 3);
      int slot = (l4 + (colp >> 1)) & 3;
      short8 sv = *reinterpret_cast<const short8*>(
          &lds_y[(sr * 64 + colp) * 32 + slot * 8]);
      if (dx == 0 && kill0) sv = z8;
      if (dx == 2 && kill2) sv = z8;
      Bc[rm][dx] = __builtin_bit_cast(bf16x8, sv);
    }
  };

  load_row(0, 0);
  load_row(1, 1);
#pragma unroll
  for (int r = 0; r < 8; ++r) {
    load_row(r + 2, (r + 2) % 3);
    f32x4 acc0 = bias0, acc1 = bias1;
#pragma unroll
    for (int t9 = 0; t9 < 9; ++t9) {
      const int dy = t9 / 3, dx = t9 - dy * 3;
      const int rm = (r + dy) % 3;   // compile-time in unrolled body
      acc0 = __builtin_amdgcn_mfma_f32_16x16x32_bf16(wf[t9 * 2], Bc[rm][dx],
                                                     acc0, 0, 0, 0);
      acc1 = __builtin_amdgcn_mfma_f32_16x16x32_bf16(wf[t9 * 2 + 1],
                                                     Bc[rm][dx], acc1, 0, 0, 0);
    }
    int grow = R * 64 + h0 + r;
    int gcol = Cc * 64 + c0 + l15;
    float* ob = out + (size_t)b * 2097152 + (size_t)grow * 256 + gcol;
#pragma unroll
    for (int i = 0; i < 4; ++i) {
      __builtin_nontemporal_store(acc0[i], &ob[(size_t)(l4 * 4 + i) * 65536]);
      __builtin_nontemporal_store(acc1[i],
                                  &ob[(size_t)(16 + l4 * 4 + i) * 65536]);
    }
  }
}

extern "C" void kernel_launch(void* const* d_in, const int* in_sizes, int n_in,
                              void* d_out, int out_size, void* d_ws,
                              size_t ws_size, hipStream_t stream) {
  const float* x = (const float*)d_in[0];
  const float* gamma = (const float*)d_in[1];
  const float* beta = (const float*)d_in[2];
  const float* prelu_a = (const float*)d_in[3];
  const float* conv_w = (const float*)d_in[4];
  const float* conv_b = (const float*)d_in[5];
  float* out = (float*)d_out;

  float* ws = (float*)d_ws;
  float* ws_sum = ws;                          // 16384 floats
  float* ws_sq = ws + 16384;                   // 16384
  unsigned short* wfrag = (unsigned short*)(ws + 32768);   // 9216 shorts

  stats_prep<<<1029, 256, 0, stream>>>(x, ws_sum, ws_sq, conv_w, wfrag);
  conv_mfma<<<4096, 256, 0, stream>>>(x, wfrag, conv_b, prelu_a, ws_sum, ws_sq,
                                      gamma, beta, out);
}